// Round 7
// baseline (206.462 us; speedup 1.0000x reference)
//
#include <hip/hip_runtime.h>

#define HIDDEN 1024
#define HEADS 16
#define HD 64
#define BATCH 2
#define SEQ 2048
#define MTOT (BATCH*SEQ)

typedef _Float16 f16;
typedef _Float16 half8 __attribute__((ext_vector_type(8)));
typedef _Float16 half4v __attribute__((ext_vector_type(4)));
typedef _Float16 half2v __attribute__((ext_vector_type(2)));
typedef float floatx4 __attribute__((ext_vector_type(4)));

// async 16B global -> LDS (dest = wave-uniform base + lane*16)
__device__ __forceinline__ void cp16(f16* lds_dst, const f16* gsrc) {
    __builtin_amdgcn_global_load_lds(
        (const __attribute__((address_space(1))) unsigned int*)gsrc,
        (__attribute__((address_space(3))) unsigned int*)lds_dst,
        16, 0, 0);
}

__device__ __forceinline__ half2v pk_f16(float a, float b) {
    return __builtin_bit_cast(half2v, __builtin_amdgcn_cvt_pkrtz(a, b));
}

// raw v_exp_f32 (no denormal-guard expansion; args are log2-domain, |x| < 50)
__device__ __forceinline__ float fast_exp2(float x) {
#if __has_builtin(__builtin_amdgcn_exp2f)
    return __builtin_amdgcn_exp2f(x);
#else
    return exp2f(x);
#endif
}

// ---------------- cast x (fp32 -> fp16) ----------------
__global__ __launch_bounds__(256) void cast_x_kernel(const float* __restrict__ x,
                                                     f16* __restrict__ xh) {
    int i = (blockIdx.x * 256 + threadIdx.x) * 4;
    floatx4 v = *(const floatx4*)(x + i);
    half4v o;
    #pragma unroll
    for (int j = 0; j < 4; ++j) o[j] = (f16)v[j];
    *(half4v*)(xh + i) = o;
}

// ------------- transpose-cast W [in][out] fp32 -> Wt [out][in] fp16 -------------
__global__ void castT_kernel(const float* __restrict__ Wq, const float* __restrict__ Wk,
                             const float* __restrict__ Wv, const float* __restrict__ Wo,
                             f16* __restrict__ wt) {
    __shared__ float tile[32][33];
    int z = blockIdx.z;
    const float* W = (z == 0) ? Wq : (z == 1) ? Wk : (z == 2) ? Wv : Wo;
    int bx = blockIdx.x, by = blockIdx.y;
    int tx = threadIdx.x, ty = threadIdx.y;
    tile[ty][tx] = W[(by * 32 + ty) * HIDDEN + bx * 32 + tx];
    __syncthreads();
    wt[(size_t)z * HIDDEN * HIDDEN + (bx * 32 + ty) * HIDDEN + by * 32 + tx] =
        (f16)tile[tx][ty];
}

// ---------------- fused QKV GEMM (BK=64, global_load_lds staging) ----------------
#define BM 128
#define BN 128
#define GBK 64

__global__ __launch_bounds__(256, 3) void gemm_qkv(const f16* __restrict__ xh,
                                                   const f16* __restrict__ wt,
                                                   const float* __restrict__ bq,
                                                   const float* __restrict__ bk,
                                                   const float* __restrict__ bv,
                                                   f16* __restrict__ qo, f16* __restrict__ ko,
                                                   f16* __restrict__ vto) {
    __shared__ f16 As[BM * GBK];
    __shared__ f16 Bs[BN * GBK];
    const int m0 = blockIdx.y * BM;
    const int n0 = blockIdx.x * BN;
    const int t = threadIdx.x;
    const int lane = t & 63, w = t >> 6;
    const int wm = w >> 1, wn = w & 1;
    const int lr = lane & 15, quad = lane >> 4;
    const int lq7 = lr & 7;

    const int baseA0 = wm * 4096 + lr * 64 + ((quad ^ lq7) * 8);
    const int baseA1 = wm * 4096 + lr * 64 + (((quad + 4) ^ lq7) * 8);
    const int baseB0 = wn * 4096 + lr * 64 + ((quad ^ lq7) * 8);
    const int baseB1 = wn * 4096 + lr * 64 + (((quad + 4) ^ lq7) * 8);

    floatx4 acc[4][4];
    #pragma unroll
    for (int i = 0; i < 4; ++i)
        #pragma unroll
        for (int j = 0; j < 4; ++j)
            #pragma unroll
            for (int r = 0; r < 4; ++r) acc[i][j][r] = 0.f;

    for (int k0 = 0; k0 < HIDDEN; k0 += GBK) {
        #pragma unroll
        for (int p = 0; p < 4; ++p) {
            int s = p * 256 + t;
            int row = s >> 3, ch = (s & 7) ^ (row & 7);
            cp16(&As[s * 8], &xh[(size_t)(m0 + row) * HIDDEN + k0 + ch * 8]);
            cp16(&Bs[s * 8], &wt[(size_t)(n0 + row) * HIDDEN + k0 + ch * 8]);
        }
        __syncthreads();
        half8 af[4], bf[4];
        #pragma unroll
        for (int i = 0; i < 4; ++i) af[i] = *(half8*)(&As[baseA0 + i * 1024]);
        #pragma unroll
        for (int j = 0; j < 4; ++j) bf[j] = *(half8*)(&Bs[baseB0 + j * 1024]);
        #pragma unroll
        for (int i = 0; i < 4; ++i)
            #pragma unroll
            for (int j = 0; j < 4; ++j)
                acc[i][j] = __builtin_amdgcn_mfma_f32_16x16x32_f16(af[i], bf[j], acc[i][j], 0, 0, 0);
        #pragma unroll
        for (int i = 0; i < 4; ++i) af[i] = *(half8*)(&As[baseA1 + i * 1024]);
        #pragma unroll
        for (int j = 0; j < 4; ++j) bf[j] = *(half8*)(&Bs[baseB1 + j * 1024]);
        #pragma unroll
        for (int i = 0; i < 4; ++i)
            #pragma unroll
            for (int j = 0; j < 4; ++j)
                acc[i][j] = __builtin_amdgcn_mfma_f32_16x16x32_f16(af[i], bf[j], acc[i][j], 0, 0, 0);
        __syncthreads();
    }

    #pragma unroll
    for (int i = 0; i < 4; ++i) {
        int mbase = m0 + wm * 64 + i * 16 + quad * 4;
        #pragma unroll
        for (int j = 0; j < 4; ++j) {
            int n = n0 + wn * 64 + j * 16 + lr;
            int proj = n >> 10;
            int c = n & 1023;
            int h = c >> 6, d = c & 63;
            const float* bp = (proj == 0) ? bq : (proj == 1) ? bk : bv;
            float bias = bp[c];
            int m = mbase;
            int b = m >> 11, s = m & 2047;
            int bh = b * HEADS + h;
            if (proj == 2) {
                half4v pv;
                #pragma unroll
                for (int r = 0; r < 4; ++r) pv[r] = (f16)(acc[i][j][r] + bias);
                *(half4v*)(&vto[((size_t)bh * HD + d) * SEQ + s]) = pv;  // natural [d][s]
            } else {
                f16* dst = (proj == 0) ? qo : ko;
                #pragma unroll
                for (int r = 0; r < 4; ++r)
                    dst[((size_t)bh * SEQ + (s + r)) * HD + d] = (f16)(acc[i][j][r] + bias);
            }
        }
    }
}

// ---------------- flash attention v16 (resubmit: round-6 bench was an infra failure) ----------------
// Theory unchanged: per-CU-per-tile pipe demand LDS 3.7k cyc (52%; each of 8
// waves ingests the full 32KB K+V tile), VALU 2.8k (39% meas), MFMA 2.5k (30%
// meas). The reducible term is LDS bytes. v16 drops V staging entirely (guide
// m169: V-stage removal when L2-resident was +26% attn): V is [d][s] in global,
// the exact layout the LDS tile mirrored, so PV fragments load directly:
//   vf[g2][nt4] = V[nt4*16+lr][kt*128 + g2*32 + quad*8 ..]   (16B/lane, 64B/quad)
// Per-XCD V working set = 4 bh x 256 KB = 1 MB << 4 MB L2. LDS pipe -> ~2.1k
// (V reads AND V cp16 writes gone). V loads are register loads: compiler tracks
// their vmcnt (incl. outstanding K cp16s) automatically; latency hides under
// QK+EXP. Numerics bitwise identical to v13/v15.
__global__ __launch_bounds__(256, 2) void attn_kernel(const f16* __restrict__ q,
                                                      const f16* __restrict__ k,
                                                      const f16* __restrict__ vt,
                                                      f16* __restrict__ ctx) {
    __shared__ f16 Klds[2][128 * 64];   // [perm-key][d] swizzled, 2 x 16 KB (V staging removed)
    const int blk = blockIdx.x;
    const int bh = blk & 31, qt = blk >> 5;   // bh low -> XCD-local
    const int t = threadIdx.x;
    const int lane = t & 63, w = t >> 6;
    const int lr = lane & 15, quad = lane >> 4;
    const int lq7 = lr & 7;

    const f16* qbh = q + (size_t)bh * SEQ * HD;
    const f16* kbh = k + (size_t)bh * SEQ * HD;
    const f16* vbh = vt + (size_t)bh * HD * SEQ;

    const int qrow = qt * 128 + w * 32;

    // hoisted LDS fragment-read bases (f16 indices), kt-invariant
    const int base_k0 = lr * 64 + ((quad ^ lq7) * 8);
    const int base_k1 = lr * 64 + (((quad + 4) ^ lq7) * 8);

    // stage K tile kt (4 global_load_lds per thread), key-permuted within 32-key groups
    auto stageK = [&](f16* Kd, int kt) {
        const f16* kbase = kbh + (size_t)kt * 128 * HD;
        #pragma unroll
        for (int p = 0; p < 4; ++p) {
            int s = p * 256 + t;
            int row = s >> 3, ch = (s & 7) ^ (row & 7);
            int wk = row & 31;
            int key = (row & ~31) | ((wk & 12) << 1) | ((wk >> 4) << 2) | (wk & 3);
            cp16(&Kd[s * 8], &kbase[(size_t)key * HD + ch * 8]);
        }
    };

    // issue tile-0 K staging first so it overlaps the Q-fragment load + scale math
    stageK(Klds[0], 0);

    // Q fragments pre-scaled by (1/8)*log2(e); group g covers queries qrow+g*16+lr
    half8 qf[2][2];
    #pragma unroll
    for (int g = 0; g < 2; ++g)
        #pragma unroll
        for (int ks = 0; ks < 2; ++ks) {
            half8 v = *(const half8*)(&qbh[(size_t)(qrow + g * 16 + lr) * HD + ks * 32 + quad * 8]);
            #pragma unroll
            for (int j = 0; j < 8; ++j) v[j] = (f16)((float)v[j] * 0.1803368801f);
            qf[g][ks] = v;
        }

    floatx4 oacc[2][4];
    float lsum[2] = {0.f, 0.f};
    #pragma unroll
    for (int g = 0; g < 2; ++g)
        #pragma unroll
        for (int nt4 = 0; nt4 < 4; ++nt4)
            #pragma unroll
            for (int r = 0; r < 4; ++r) oacc[g][nt4][r] = 0.f;

    // tile 0 staged by all waves before first compute
    asm volatile("s_waitcnt vmcnt(0)" ::: "memory");
    __builtin_amdgcn_s_barrier();
    asm volatile("" ::: "memory");

    for (int kt = 0; kt < 16; ++kt) {
        const int cur = kt & 1;

        // ---- V fragments for THIS tile, direct from global (L2-resident) ----
        // issued first so they have the whole QK+EXP phase to land
        const f16* vb = vbh + (size_t)kt * 128;   // [d][s], kt advances s by 128
        half8 vf[4][4];   // [g2][nt4]
        #pragma unroll
        for (int g2 = 0; g2 < 4; ++g2)
            #pragma unroll
            for (int nt4 = 0; nt4 < 4; ++nt4)
                vf[g2][nt4] = *(const half8*)(&vb[(size_t)(nt4 * 16 + lr) * SEQ + g2 * 32 + quad * 8]);

        // prefetch next K tile into the other buffer; stays in flight across compute
        if (kt < 15) stageK(Klds[cur ^ 1], kt + 1);
        f16* Kl = Klds[cur];

        // ---- Phase A: batch all K fragment reads (16 x ds_read_b128) ----
        half8 kf[8][2];
        #pragma unroll
        for (int t2 = 0; t2 < 8; ++t2) {
            kf[t2][0] = *(half8*)(&Kl[base_k0 + t2 * 1024]);
            kf[t2][1] = *(half8*)(&Kl[base_k1 + t2 * 1024]);
        }

        // ---- Phase B: all QK^T MFMAs (16 independent 2-deep chains) ----
        floatx4 sc[8][2];
        #pragma unroll
        for (int t2 = 0; t2 < 8; ++t2) {
            #pragma unroll
            for (int g = 0; g < 2; ++g) {
                floatx4 s = {0.f, 0.f, 0.f, 0.f};
                s = __builtin_amdgcn_mfma_f32_16x16x32_f16(kf[t2][0], qf[g][0], s, 0, 0, 0);
                s = __builtin_amdgcn_mfma_f32_16x16x32_f16(kf[t2][1], qf[g][1], s, 0, 0, 0);
                sc[t2][g] = s;
            }
        }

        // ---- Phase C: all exps + packs (fully independent) ----
        half8 p8[4][2];
        #pragma unroll
        for (int g2 = 0; g2 < 4; ++g2) {
            #pragma unroll
            for (int g = 0; g < 2; ++g) {
                floatx4 s0 = sc[2 * g2][g], s1 = sc[2 * g2 + 1][g];
                float pa0 = fast_exp2(s0[0]), pa1 = fast_exp2(s0[1]);
                float pa2 = fast_exp2(s0[2]), pa3 = fast_exp2(s0[3]);
                float pb0 = fast_exp2(s1[0]), pb1 = fast_exp2(s1[1]);
                float pb2 = fast_exp2(s1[2]), pb3 = fast_exp2(s1[3]);
                lsum[g] += ((pa0 + pa1) + (pa2 + pa3)) + ((pb0 + pb1) + (pb2 + pb3));
                half4v pa = __builtin_shufflevector(pk_f16(pa0, pa1), pk_f16(pa2, pa3), 0, 1, 2, 3);
                half4v pb = __builtin_shufflevector(pk_f16(pb0, pb1), pk_f16(pb2, pb3), 0, 1, 2, 3);
                p8[g2][g] = __builtin_shufflevector(pa, pb, 0, 1, 2, 3, 4, 5, 6, 7);
            }
        }

        // ---- Phase D: all PV MFMAs (vf already in registers) ----
        #pragma unroll
        for (int g2 = 0; g2 < 4; ++g2)
            #pragma unroll
            for (int nt4 = 0; nt4 < 4; ++nt4) {
                oacc[0][nt4] = __builtin_amdgcn_mfma_f32_16x16x32_f16(vf[g2][nt4], p8[g2][0], oacc[0][nt4], 0, 0, 0);
                oacc[1][nt4] = __builtin_amdgcn_mfma_f32_16x16x32_f16(vf[g2][nt4], p8[g2][1], oacc[1][nt4], 0, 0, 0);
            }

        // single end-of-tile sync: (a) K prefetch for kt+1 landed (per-wave vmcnt + barrier),
        // (b) all waves done reading Klds[cur] before kt+1 overwrites it.
        asm volatile("s_waitcnt vmcnt(0)" ::: "memory");
        __builtin_amdgcn_s_barrier();
        asm volatile("" ::: "memory");
    }

    // epilogue: reduce lsum over quad-copies, normalize, store
    const int b = bh >> 4, h = bh & 15;
    #pragma unroll
    for (int g = 0; g < 2; ++g) {
        float s = lsum[g];
        s += __shfl_xor(s, 16, 64);
        s += __shfl_xor(s, 32, 64);
        float inv = 1.f / s;
        #pragma unroll
        for (int nt4 = 0; nt4 < 4; ++nt4) {
            half4v o4;
            #pragma unroll
            for (int r = 0; r < 4; ++r) o4[r] = (f16)(oacc[g][nt4][r] * inv);
            *(half4v*)(&ctx[((size_t)(b * SEQ + qrow + g * 16 + lr)) * HIDDEN + h * HD + nt4 * 16 + quad * 4]) = o4;
        }
    }
}

// ---------------- output projection GEMM (64x128 tiles, BK=64, fp32 out) ----------------
#define OBM 64
__global__ __launch_bounds__(256, 4) void gemm_out(const f16* __restrict__ ah,
                                                   const f16* __restrict__ wto,
                                                   const float* __restrict__ bo,
                                                   float* __restrict__ out) {
    __shared__ f16 As[OBM * GBK];   // 8 KB
    __shared__ f16 Bs[BN * GBK];    // 16 KB
    const int m0 = blockIdx.y * OBM;
    const int n0 = blockIdx.x * BN;
    const int t = threadIdx.x;
    const int lane = t & 63, w = t >> 6;
    const int wm = w >> 1, wn = w & 1;   // wave tile: 32 m x 64 n
    const int lr = lane & 15, quad = lane >> 4;
    const int lq7 = lr & 7;

    const int baseA0 = wm * 2048 + lr * 64 + ((quad ^ lq7) * 8);
    const int baseA1 = wm * 2048 + lr * 64 + (((quad + 4) ^ lq7) * 8);
    const int baseB0 = wn * 4096 + lr * 64 + ((quad ^ lq7) * 8);
    const int baseB1 = wn * 4096 + lr * 64 + (((quad + 4) ^ lq7) * 8);

    floatx4 acc[2][4];
    #pragma unroll
    for (int i = 0; i < 2; ++i)
        #pragma unroll
        for (int j = 0; j < 4; ++j)
            #pragma unroll
            for (int r = 0; r < 4; ++r) acc[i][j][r] = 0.f;

    for (int k0 = 0; k0 < HIDDEN; k0 += GBK) {
        #pragma unroll
        for (int p = 0; p < 2; ++p) {
            int s = p * 256 + t;
            int row = s >> 3, ch = (s & 7) ^ (row & 7);
            cp16(&As[s * 8], &ah[(size_t)(m0 + row) * HIDDEN + k0 + ch * 8]);
        }
        #pragma unroll
        for (int p = 0; p < 4; ++p) {
            int s = p * 256 + t;
            int row = s >> 3, ch = (s & 7) ^ (row & 7);
            cp16(&Bs[s * 8], &wto[(size_t)(n0 + row) * HIDDEN + k0 + ch * 8]);
        }
        __syncthreads();
        half8 af[2], bf[4];
        #pragma unroll
        for (int i = 0; i < 2; ++i) af[i] = *(half8*)(&As[baseA0 + i * 1024]);
        #pragma unroll
        for (int j = 0; j < 4; ++j) bf[j] = *(half8*)(&Bs[baseB0 + j * 1024]);
        #pragma unroll
        for (int i = 0; i < 2; ++i)
            #pragma unroll
            for (int j = 0; j < 4; ++j)
                acc[i][j] = __builtin_amdgcn_mfma_f32_16x16x32_f16(af[i], bf[j], acc[i][j], 0, 0, 0);
        #pragma unroll
        for (int i = 0; i < 2; ++i) af[i] = *(half8*)(&As[baseA1 + i * 1024]);
        #pragma unroll
        for (int j = 0; j < 4; ++j) bf[j] = *(half8*)(&Bs[baseB1 + j * 1024]);
        #pragma unroll
        for (int i = 0; i < 2; ++i)
            #pragma unroll
            for (int j = 0; j < 4; ++j)
                acc[i][j] = __builtin_amdgcn_mfma_f32_16x16x32_f16(af[i], bf[j], acc[i][j], 0, 0, 0);
        __syncthreads();
    }

    #pragma unroll
    for (int i = 0; i < 2; ++i) {
        int mbase = m0 + wm * 32 + i * 16 + quad * 4;
        #pragma unroll
        for (int j = 0; j < 4; ++j) {
            int n = n0 + wn * 64 + j * 16 + lr;
            float bias = bo[n];
            #pragma unroll
            for (int r = 0; r < 4; ++r)
                out[(size_t)(mbase + r) * HIDDEN + n] = acc[i][j][r] + bias;
        }
    }
}

// ---------------- launch ----------------
extern "C" void kernel_launch(void* const* d_in, const int* in_sizes, int n_in,
                              void* d_out, int out_size, void* d_ws, size_t ws_size,
                              hipStream_t stream) {
    const float* x  = (const float*)d_in[0];
    const float* Wq = (const float*)d_in[1];
    const float* bq = (const float*)d_in[2];
    const float* Wk = (const float*)d_in[3];
    const float* bk = (const float*)d_in[4];
    const float* Wv = (const float*)d_in[5];
    const float* bv = (const float*)d_in[6];
    const float* Wo = (const float*)d_in[7];
    const float* bo = (const float*)d_in[8];
    float* out = (float*)d_out;

    char* ws = (char*)d_ws;
    f16* xh   = (f16*)(ws);                   // 8 MB
    f16* wt   = (f16*)(ws + (8u  << 20));     // 8 MB
    f16* qw   = (f16*)(ws + (16u << 20));     // 8 MB
    f16* kw   = (f16*)(ws + (24u << 20));     // 8 MB
    f16* vtw  = (f16*)(ws + (32u << 20));     // 8 MB (natural [d][s] layout)
    f16* ctxh = (f16*)(ws + (40u << 20));     // 8 MB

    cast_x_kernel<<<MTOT * HIDDEN / 1024, 256, 0, stream>>>(x, xh);
    castT_kernel<<<dim3(32, 32, 4), dim3(32, 32), 0, stream>>>(Wq, Wk, Wv, Wo, wt);
    gemm_qkv<<<dim3(3 * HIDDEN / BN, MTOT / BM), 256, 0, stream>>>(xh, wt, bq, bk, bv, qw, kw, vtw);
    attn_kernel<<<32 * (SEQ / 128), 256, 0, stream>>>(qw, kw, vtw, ctxh);
    gemm_out<<<dim3(HIDDEN / BN, MTOT / OBM), 256, 0, stream>>>(ctxh, wt + (size_t)3 * HIDDEN * HIDDEN, bo, out);
}

// Round 8
// 185.510 us; speedup vs baseline: 1.1129x; 1.1129x over previous
//
#include <hip/hip_runtime.h>

#define HIDDEN 1024
#define HEADS 16
#define HD 64
#define BATCH 2
#define SEQ 2048
#define MTOT (BATCH*SEQ)

typedef _Float16 f16;
typedef _Float16 half8 __attribute__((ext_vector_type(8)));
typedef _Float16 half4v __attribute__((ext_vector_type(4)));
typedef _Float16 half2v __attribute__((ext_vector_type(2)));
typedef float floatx4 __attribute__((ext_vector_type(4)));

// async 16B global -> LDS (dest = wave-uniform base + lane*16)
__device__ __forceinline__ void cp16(f16* lds_dst, const f16* gsrc) {
    __builtin_amdgcn_global_load_lds(
        (const __attribute__((address_space(1))) unsigned int*)gsrc,
        (__attribute__((address_space(3))) unsigned int*)lds_dst,
        16, 0, 0);
}

__device__ __forceinline__ half2v pk_f16(float a, float b) {
    return __builtin_bit_cast(half2v, __builtin_amdgcn_cvt_pkrtz(a, b));
}

// raw v_exp_f32 (no denormal-guard expansion; args are log2-domain, |x| < 50)
__device__ __forceinline__ float fast_exp2(float x) {
#if __has_builtin(__builtin_amdgcn_exp2f)
    return __builtin_amdgcn_exp2f(x);
#else
    return exp2f(x);
#endif
}

// ---------------- cast x (fp32 -> fp16) ----------------
__global__ __launch_bounds__(256) void cast_x_kernel(const float* __restrict__ x,
                                                     f16* __restrict__ xh) {
    int i = (blockIdx.x * 256 + threadIdx.x) * 4;
    floatx4 v = *(const floatx4*)(x + i);
    half4v o;
    #pragma unroll
    for (int j = 0; j < 4; ++j) o[j] = (f16)v[j];
    *(half4v*)(xh + i) = o;
}

// ------------- transpose-cast W [in][out] fp32 -> Wt [out][in] fp16 -------------
__global__ void castT_kernel(const float* __restrict__ Wq, const float* __restrict__ Wk,
                             const float* __restrict__ Wv, const float* __restrict__ Wo,
                             f16* __restrict__ wt) {
    __shared__ float tile[32][33];
    int z = blockIdx.z;
    const float* W = (z == 0) ? Wq : (z == 1) ? Wk : (z == 2) ? Wv : Wo;
    int bx = blockIdx.x, by = blockIdx.y;
    int tx = threadIdx.x, ty = threadIdx.y;
    tile[ty][tx] = W[(by * 32 + ty) * HIDDEN + bx * 32 + tx];
    __syncthreads();
    wt[(size_t)z * HIDDEN * HIDDEN + (bx * 32 + ty) * HIDDEN + by * 32 + tx] =
        (f16)tile[tx][ty];
}

// ---------------- fused QKV GEMM (BK=64, global_load_lds staging) ----------------
#define BM 128
#define BN 128
#define GBK 64

__global__ __launch_bounds__(256, 3) void gemm_qkv(const f16* __restrict__ xh,
                                                   const f16* __restrict__ wt,
                                                   const float* __restrict__ bq,
                                                   const float* __restrict__ bk,
                                                   const float* __restrict__ bv,
                                                   f16* __restrict__ qo, f16* __restrict__ ko,
                                                   f16* __restrict__ vto) {
    __shared__ f16 As[BM * GBK];
    __shared__ f16 Bs[BN * GBK];
    const int m0 = blockIdx.y * BM;
    const int n0 = blockIdx.x * BN;
    const int t = threadIdx.x;
    const int lane = t & 63, w = t >> 6;
    const int wm = w >> 1, wn = w & 1;
    const int lr = lane & 15, quad = lane >> 4;
    const int lq7 = lr & 7;

    const int baseA0 = wm * 4096 + lr * 64 + ((quad ^ lq7) * 8);
    const int baseA1 = wm * 4096 + lr * 64 + (((quad + 4) ^ lq7) * 8);
    const int baseB0 = wn * 4096 + lr * 64 + ((quad ^ lq7) * 8);
    const int baseB1 = wn * 4096 + lr * 64 + (((quad + 4) ^ lq7) * 8);

    floatx4 acc[4][4];
    #pragma unroll
    for (int i = 0; i < 4; ++i)
        #pragma unroll
        for (int j = 0; j < 4; ++j)
            #pragma unroll
            for (int r = 0; r < 4; ++r) acc[i][j][r] = 0.f;

    for (int k0 = 0; k0 < HIDDEN; k0 += GBK) {
        #pragma unroll
        for (int p = 0; p < 4; ++p) {
            int s = p * 256 + t;
            int row = s >> 3, ch = (s & 7) ^ (row & 7);
            cp16(&As[s * 8], &xh[(size_t)(m0 + row) * HIDDEN + k0 + ch * 8]);
            cp16(&Bs[s * 8], &wt[(size_t)(n0 + row) * HIDDEN + k0 + ch * 8]);
        }
        __syncthreads();
        half8 af[4], bf[4];
        #pragma unroll
        for (int i = 0; i < 4; ++i) af[i] = *(half8*)(&As[baseA0 + i * 1024]);
        #pragma unroll
        for (int j = 0; j < 4; ++j) bf[j] = *(half8*)(&Bs[baseB0 + j * 1024]);
        #pragma unroll
        for (int i = 0; i < 4; ++i)
            #pragma unroll
            for (int j = 0; j < 4; ++j)
                acc[i][j] = __builtin_amdgcn_mfma_f32_16x16x32_f16(af[i], bf[j], acc[i][j], 0, 0, 0);
        #pragma unroll
        for (int i = 0; i < 4; ++i) af[i] = *(half8*)(&As[baseA1 + i * 1024]);
        #pragma unroll
        for (int j = 0; j < 4; ++j) bf[j] = *(half8*)(&Bs[baseB1 + j * 1024]);
        #pragma unroll
        for (int i = 0; i < 4; ++i)
            #pragma unroll
            for (int j = 0; j < 4; ++j)
                acc[i][j] = __builtin_amdgcn_mfma_f32_16x16x32_f16(af[i], bf[j], acc[i][j], 0, 0, 0);
        __syncthreads();
    }

    #pragma unroll
    for (int i = 0; i < 4; ++i) {
        int mbase = m0 + wm * 64 + i * 16 + quad * 4;
        #pragma unroll
        for (int j = 0; j < 4; ++j) {
            int n = n0 + wn * 64 + j * 16 + lr;
            int proj = n >> 10;
            int c = n & 1023;
            int h = c >> 6, d = c & 63;
            const float* bp = (proj == 0) ? bq : (proj == 1) ? bk : bv;
            float bias = bp[c];
            int m = mbase;
            int b = m >> 11, s = m & 2047;
            int bh = b * HEADS + h;
            if (proj == 2) {
                half4v pv;
                #pragma unroll
                for (int r = 0; r < 4; ++r) pv[r] = (f16)(acc[i][j][r] + bias);
                *(half4v*)(&vto[((size_t)bh * HD + d) * SEQ + s]) = pv;  // natural [d][s]
            } else {
                f16* dst = (proj == 0) ? qo : ko;
                #pragma unroll
                for (int r = 0; r < 4; ++r)
                    dst[((size_t)bh * SEQ + (s + r)) * HD + d] = (f16)(acc[i][j][r] + bias);
            }
        }
    }
}

// ---------------- flash attention v17: 8-wave block, split-K within block ----------------
// v16 post-mortem: V-from-L2 regressed 60% (per-CU L2 BW ~56 B/cyc < LDS 85-128;
// latency exposed at 2 blocks/CU). Reverted to LDS staging. v17 attacks the real
// limiter: poor pipe overlap at 8 waves/CU. Block = 512 threads (8 waves) =
// 4 q-groups x 2 key-halves over the same 128x128 tile:
//   wave (qw,kh): q-rows qw*32..+31, keys kh*64..+63 of each kt tile.
// Per-wave work halves; per-CU totals (LDS reads 256KB/tile, stage 64KB, 512
// MFMAs, exps) are IDENTICAL to v13 -- but 16 waves/CU instead of 8 to overlap
// the three ~equal pipes (MFMA 2.5k / VALU 2.8k / LDS 3.7k cyc per CU-tile).
// Fixed-max softmax => oacc/lsum partials exactly additive; kh pairs combine
// ONCE at the end via a 32KB LDS exchange (no global partials -> no v14 blowup).
// LDS 64KB/block -> 2 blocks/CU; __launch_bounds__(512,4) caps VGPR at 128.
__global__ __launch_bounds__(512, 4) void attn_kernel(const f16* __restrict__ q,
                                                      const f16* __restrict__ k,
                                                      const f16* __restrict__ vt,
                                                      f16* __restrict__ ctx) {
    __shared__ __align__(16) f16 Klds[2][128 * 64];   // [perm-key][d] swizzled, 2 x 16 KB
    __shared__ __align__(16) f16 Vlds[2][64 * 128];   // [d][s] swizzled, 2 x 16 KB
    const int blk = blockIdx.x;
    const int bh = blk & 31, qt = blk >> 5;   // bh low -> XCD-local
    const int t = threadIdx.x;
    const int lane = t & 63, w = t >> 6;      // 8 waves
    const int qw = w >> 1, kh = w & 1;        // q-group, key-half
    const int lr = lane & 15, quad = lane >> 4;
    const int lq7 = lr & 7;

    const f16* qbh = q + (size_t)bh * SEQ * HD;
    const f16* kbh = k + (size_t)bh * SEQ * HD;
    const f16* vbh = vt + (size_t)bh * HD * SEQ;

    const int qrow = qt * 128 + qw * 32;

    // K fragment bases: key-half kh covers t2-blocks 4*kh..4*kh+3 (f16 offset 4096*kh)
    const int base_k0 = kh * 4096 + lr * 64 + ((quad ^ lq7) * 8);
    const int base_k1 = kh * 4096 + lr * 64 + (((quad + 4) ^ lq7) * 8);
    // V fragment bases for the 2 local key-groups (global g2 = 2*kh + g2l)
    int voff[2];
    #pragma unroll
    for (int g2l = 0; g2l < 2; ++g2l) {
        int g2 = 2 * kh + g2l;
        voff[g2l] = lr * 128 + (((g2 * 4 + quad) ^ lr) * 8);
    }

    // stage tile kt into (Kd, Vd): 4 global_load_lds per thread (2 K + 2 V), 512 threads
    auto stage = [&](f16* Kd, f16* Vd, int kt) {
        const f16* kbase = kbh + (size_t)kt * 128 * HD;
        const f16* vbase = vbh + (size_t)kt * 128;
        #pragma unroll
        for (int p = 0; p < 2; ++p) {
            int s = p * 512 + t;
            int row = s >> 3, ch = (s & 7) ^ (row & 7);
            int wk = row & 31;
            int key = (row & ~31) | ((wk & 12) << 1) | ((wk >> 4) << 2) | (wk & 3);
            cp16(&Kd[s * 8], &kbase[(size_t)key * HD + ch * 8]);
        }
        #pragma unroll
        for (int p = 0; p < 2; ++p) {
            int s = p * 512 + t;
            int row = s >> 4, ch = (s & 15) ^ (row & 15);
            cp16(&Vd[s * 8], &vbase[(size_t)row * SEQ + ch * 8]);
        }
    };

    // issue tile-0 staging first so it overlaps the Q-fragment load + scale math
    stage(Klds[0], Vlds[0], 0);

    // Q fragments pre-scaled by (1/8)*log2(e); group g covers queries qrow+g*16+lr
    half8 qf[2][2];
    #pragma unroll
    for (int g = 0; g < 2; ++g)
        #pragma unroll
        for (int ks = 0; ks < 2; ++ks) {
            half8 v = *(const half8*)(&qbh[(size_t)(qrow + g * 16 + lr) * HD + ks * 32 + quad * 8]);
            #pragma unroll
            for (int j = 0; j < 8; ++j) v[j] = (f16)((float)v[j] * 0.1803368801f);
            qf[g][ks] = v;
        }

    floatx4 oacc[2][4];
    float lsum[2] = {0.f, 0.f};
    #pragma unroll
    for (int g = 0; g < 2; ++g)
        #pragma unroll
        for (int nt4 = 0; nt4 < 4; ++nt4)
            #pragma unroll
            for (int r = 0; r < 4; ++r) oacc[g][nt4][r] = 0.f;

    // tile 0 staged by all waves before first compute
    asm volatile("s_waitcnt vmcnt(0)" ::: "memory");
    __builtin_amdgcn_s_barrier();
    asm volatile("" ::: "memory");

    for (int kt = 0; kt < 16; ++kt) {
        const int cur = kt & 1;
        // prefetch next tile into the other buffer; loads stay in flight across compute
        if (kt < 15) stage(Klds[cur ^ 1], Vlds[cur ^ 1], kt + 1);
        f16* Kl = Klds[cur];
        f16* Vl = Vlds[cur];

        // ---- Phase A: K fragment reads for this wave's key-half (8 x ds_read_b128) ----
        half8 kf[4][2];
        #pragma unroll
        for (int j = 0; j < 4; ++j) {
            kf[j][0] = *(half8*)(&Kl[base_k0 + j * 1024]);
            kf[j][1] = *(half8*)(&Kl[base_k1 + j * 1024]);
        }

        // ---- Phase B: QK^T MFMAs (8 independent 2-deep chains) ----
        floatx4 sc[4][2];
        #pragma unroll
        for (int j = 0; j < 4; ++j) {
            #pragma unroll
            for (int g = 0; g < 2; ++g) {
                floatx4 s = {0.f, 0.f, 0.f, 0.f};
                s = __builtin_amdgcn_mfma_f32_16x16x32_f16(kf[j][0], qf[g][0], s, 0, 0, 0);
                s = __builtin_amdgcn_mfma_f32_16x16x32_f16(kf[j][1], qf[g][1], s, 0, 0, 0);
                sc[j][g] = s;
            }
        }

        // ---- Phase C: exps + packs ----
        half8 p8[2][2];
        #pragma unroll
        for (int g2l = 0; g2l < 2; ++g2l) {
            #pragma unroll
            for (int g = 0; g < 2; ++g) {
                floatx4 s0 = sc[2 * g2l][g], s1 = sc[2 * g2l + 1][g];
                float pa0 = fast_exp2(s0[0]), pa1 = fast_exp2(s0[1]);
                float pa2 = fast_exp2(s0[2]), pa3 = fast_exp2(s0[3]);
                float pb0 = fast_exp2(s1[0]), pb1 = fast_exp2(s1[1]);
                float pb2 = fast_exp2(s1[2]), pb3 = fast_exp2(s1[3]);
                lsum[g] += ((pa0 + pa1) + (pa2 + pa3)) + ((pb0 + pb1) + (pb2 + pb3));
                half4v pa = __builtin_shufflevector(pk_f16(pa0, pa1), pk_f16(pa2, pa3), 0, 1, 2, 3);
                half4v pb = __builtin_shufflevector(pk_f16(pb0, pb1), pk_f16(pb2, pb3), 0, 1, 2, 3);
                p8[g2l][g] = __builtin_shufflevector(pa, pb, 0, 1, 2, 3, 4, 5, 6, 7);
            }
        }

        // ---- Phase D: V reads for this key-half, then PV MFMAs ----
        half8 vf[2][4];
        #pragma unroll
        for (int g2l = 0; g2l < 2; ++g2l)
            #pragma unroll
            for (int nt4 = 0; nt4 < 4; ++nt4)
                vf[g2l][nt4] = *(half8*)(&Vl[voff[g2l] + nt4 * 2048]);
        #pragma unroll
        for (int g2l = 0; g2l < 2; ++g2l)
            #pragma unroll
            for (int nt4 = 0; nt4 < 4; ++nt4) {
                oacc[0][nt4] = __builtin_amdgcn_mfma_f32_16x16x32_f16(vf[g2l][nt4], p8[g2l][0], oacc[0][nt4], 0, 0, 0);
                oacc[1][nt4] = __builtin_amdgcn_mfma_f32_16x16x32_f16(vf[g2l][nt4], p8[g2l][1], oacc[1][nt4], 0, 0, 0);
            }

        // single end-of-tile sync: (a) prefetch for kt+1 landed (per-wave vmcnt + barrier),
        // (b) all waves done reading buf[cur] before kt+1 overwrites it.
        asm volatile("s_waitcnt vmcnt(0)" ::: "memory");
        __builtin_amdgcn_s_barrier();
        asm volatile("" ::: "memory");
    }

    // ---- combine kh partials via LDS (once), then normalize + store ----
    // All ds_reads of the loop completed before its final barrier; Klds/Vlds reusable.
    floatx4* XO = (floatx4*)(&Klds[0][0]);   // 8 x 256 floatx4 = 32 KB (oacc exchange)
    float*   XL = (float*)(&Vlds[0][0]);     // 2 KB (lsum exchange)
    if (kh == 1) {
        #pragma unroll
        for (int g = 0; g < 2; ++g)
            #pragma unroll
            for (int nt4 = 0; nt4 < 4; ++nt4)
                XO[(g * 4 + nt4) * 256 + qw * 64 + lane] = oacc[g][nt4];
        XL[(qw * 64 + lane) * 2 + 0] = lsum[0];
        XL[(qw * 64 + lane) * 2 + 1] = lsum[1];
    }
    __syncthreads();
    if (kh == 0) {
        #pragma unroll
        for (int g = 0; g < 2; ++g)
            #pragma unroll
            for (int nt4 = 0; nt4 < 4; ++nt4) {
                floatx4 o = XO[(g * 4 + nt4) * 256 + qw * 64 + lane];
                #pragma unroll
                for (int r = 0; r < 4; ++r) oacc[g][nt4][r] += o[r];
            }
        lsum[0] += XL[(qw * 64 + lane) * 2 + 0];
        lsum[1] += XL[(qw * 64 + lane) * 2 + 1];

        const int b = bh >> 4, h = bh & 15;
        #pragma unroll
        for (int g = 0; g < 2; ++g) {
            float s = lsum[g];
            s += __shfl_xor(s, 16, 64);
            s += __shfl_xor(s, 32, 64);
            float inv = 1.f / s;
            #pragma unroll
            for (int nt4 = 0; nt4 < 4; ++nt4) {
                half4v o4;
                #pragma unroll
                for (int r = 0; r < 4; ++r) o4[r] = (f16)(oacc[g][nt4][r] * inv);
                *(half4v*)(&ctx[((size_t)(b * SEQ + qrow + g * 16 + lr)) * HIDDEN + h * HD + nt4 * 16 + quad * 4]) = o4;
            }
        }
    }
}

// ---------------- output projection GEMM (64x128 tiles, BK=64, fp32 out) ----------------
#define OBM 64
__global__ __launch_bounds__(256, 4) void gemm_out(const f16* __restrict__ ah,
                                                   const f16* __restrict__ wto,
                                                   const float* __restrict__ bo,
                                                   float* __restrict__ out) {
    __shared__ f16 As[OBM * GBK];   // 8 KB
    __shared__ f16 Bs[BN * GBK];    // 16 KB
    const int m0 = blockIdx.y * OBM;
    const int n0 = blockIdx.x * BN;
    const int t = threadIdx.x;
    const int lane = t & 63, w = t >> 6;
    const int wm = w >> 1, wn = w & 1;   // wave tile: 32 m x 64 n
    const int lr = lane & 15, quad = lane >> 4;
    const int lq7 = lr & 7;

    const int baseA0 = wm * 2048 + lr * 64 + ((quad ^ lq7) * 8);
    const int baseA1 = wm * 2048 + lr * 64 + (((quad + 4) ^ lq7) * 8);
    const int baseB0 = wn * 4096 + lr * 64 + ((quad ^ lq7) * 8);
    const int baseB1 = wn * 4096 + lr * 64 + (((quad + 4) ^ lq7) * 8);

    floatx4 acc[2][4];
    #pragma unroll
    for (int i = 0; i < 2; ++i)
        #pragma unroll
        for (int j = 0; j < 4; ++j)
            #pragma unroll
            for (int r = 0; r < 4; ++r) acc[i][j][r] = 0.f;

    for (int k0 = 0; k0 < HIDDEN; k0 += GBK) {
        #pragma unroll
        for (int p = 0; p < 2; ++p) {
            int s = p * 256 + t;
            int row = s >> 3, ch = (s & 7) ^ (row & 7);
            cp16(&As[s * 8], &ah[(size_t)(m0 + row) * HIDDEN + k0 + ch * 8]);
        }
        #pragma unroll
        for (int p = 0; p < 4; ++p) {
            int s = p * 256 + t;
            int row = s >> 3, ch = (s & 7) ^ (row & 7);
            cp16(&Bs[s * 8], &wto[(size_t)(n0 + row) * HIDDEN + k0 + ch * 8]);
        }
        __syncthreads();
        half8 af[2], bf[4];
        #pragma unroll
        for (int i = 0; i < 2; ++i) af[i] = *(half8*)(&As[baseA0 + i * 1024]);
        #pragma unroll
        for (int j = 0; j < 4; ++j) bf[j] = *(half8*)(&Bs[baseB0 + j * 1024]);
        #pragma unroll
        for (int i = 0; i < 2; ++i)
            #pragma unroll
            for (int j = 0; j < 4; ++j)
                acc[i][j] = __builtin_amdgcn_mfma_f32_16x16x32_f16(af[i], bf[j], acc[i][j], 0, 0, 0);
        #pragma unroll
        for (int i = 0; i < 2; ++i) af[i] = *(half8*)(&As[baseA1 + i * 1024]);
        #pragma unroll
        for (int j = 0; j < 4; ++j) bf[j] = *(half8*)(&Bs[baseB1 + j * 1024]);
        #pragma unroll
        for (int i = 0; i < 2; ++i)
            #pragma unroll
            for (int j = 0; j < 4; ++j)
                acc[i][j] = __builtin_amdgcn_mfma_f32_16x16x32_f16(af[i], bf[j], acc[i][j], 0, 0, 0);
        __syncthreads();
    }

    #pragma unroll
    for (int i = 0; i < 2; ++i) {
        int mbase = m0 + wm * 32 + i * 16 + quad * 4;
        #pragma unroll
        for (int j = 0; j < 4; ++j) {
            int n = n0 + wn * 64 + j * 16 + lr;
            float bias = bo[n];
            #pragma unroll
            for (int r = 0; r < 4; ++r)
                out[(size_t)(mbase + r) * HIDDEN + n] = acc[i][j][r] + bias;
        }
    }
}

// ---------------- launch ----------------
extern "C" void kernel_launch(void* const* d_in, const int* in_sizes, int n_in,
                              void* d_out, int out_size, void* d_ws, size_t ws_size,
                              hipStream_t stream) {
    const float* x  = (const float*)d_in[0];
    const float* Wq = (const float*)d_in[1];
    const float* bq = (const float*)d_in[2];
    const float* Wk = (const float*)d_in[3];
    const float* bk = (const float*)d_in[4];
    const float* Wv = (const float*)d_in[5];
    const float* bv = (const float*)d_in[6];
    const float* Wo = (const float*)d_in[7];
    const float* bo = (const float*)d_in[8];
    float* out = (float*)d_out;

    char* ws = (char*)d_ws;
    f16* xh   = (f16*)(ws);                   // 8 MB
    f16* wt   = (f16*)(ws + (8u  << 20));     // 8 MB
    f16* qw   = (f16*)(ws + (16u << 20));     // 8 MB
    f16* kw   = (f16*)(ws + (24u << 20));     // 8 MB
    f16* vtw  = (f16*)(ws + (32u << 20));     // 8 MB (natural [d][s] layout)
    f16* ctxh = (f16*)(ws + (40u << 20));     // 8 MB

    cast_x_kernel<<<MTOT * HIDDEN / 1024, 256, 0, stream>>>(x, xh);
    castT_kernel<<<dim3(32, 32, 4), dim3(32, 32), 0, stream>>>(Wq, Wk, Wv, Wo, wt);
    gemm_qkv<<<dim3(3 * HIDDEN / BN, MTOT / BM), 256, 0, stream>>>(xh, wt, bq, bk, bv, qw, kw, vtw);
    attn_kernel<<<32 * (SEQ / 128), 512, 0, stream>>>(qw, kw, vtw, ctxh);
    gemm_out<<<dim3(HIDDEN / BN, MTOT / OBM), 256, 0, stream>>>(ctxh, wt + (size_t)3 * HIDDEN * HIDDEN, bo, out);
}

// Round 9
// 177.585 us; speedup vs baseline: 1.1626x; 1.0446x over previous
//
#include <hip/hip_runtime.h>

#define HIDDEN 1024
#define HEADS 16
#define HD 64
#define BATCH 2
#define SEQ 2048
#define MTOT (BATCH*SEQ)

typedef _Float16 f16;
typedef _Float16 half8 __attribute__((ext_vector_type(8)));
typedef _Float16 half4v __attribute__((ext_vector_type(4)));
typedef _Float16 half2v __attribute__((ext_vector_type(2)));
typedef float floatx4 __attribute__((ext_vector_type(4)));

// async 16B global -> LDS (dest = wave-uniform base + lane*16)
__device__ __forceinline__ void cp16(f16* lds_dst, const f16* gsrc) {
    __builtin_amdgcn_global_load_lds(
        (const __attribute__((address_space(1))) unsigned int*)gsrc,
        (__attribute__((address_space(3))) unsigned int*)lds_dst,
        16, 0, 0);
}

__device__ __forceinline__ half2v pk_f16(float a, float b) {
    return __builtin_bit_cast(half2v, __builtin_amdgcn_cvt_pkrtz(a, b));
}

// raw v_exp_f32 (no denormal-guard expansion; args are log2-domain, |x| < 50)
__device__ __forceinline__ float fast_exp2(float x) {
#if __has_builtin(__builtin_amdgcn_exp2f)
    return __builtin_amdgcn_exp2f(x);
#else
    return exp2f(x);
#endif
}

// ---------------- fused prep: x fp32->f16 cast + W transpose-cast (v18) ----------------
// Replaces cast_x_kernel + castT_kernel (5 launches -> 4). Blocks [0,4096): x cast,
// float4/thread. Blocks [4096,5120): 64x64 transpose tiles of Wq/Wk/Wv/Wo with
// 256 threads (old castT used 1024-thread blocks), float4 loads, LDS bounce,
// half4v stores (128 B contiguous per 16 lanes).
__global__ __launch_bounds__(256) void prep_kernel(const float* __restrict__ x,
                                                   const float* __restrict__ Wq,
                                                   const float* __restrict__ Wk,
                                                   const float* __restrict__ Wv,
                                                   const float* __restrict__ Wo,
                                                   f16* __restrict__ xh,
                                                   f16* __restrict__ wt) {
    const int bid = blockIdx.x;
    const int t = threadIdx.x;
    if (bid < 4096) {                       // ---- x cast: 4096 blocks x 1024 elems ----
        int i = (bid * 256 + t) * 4;
        floatx4 v = *(const floatx4*)(x + i);
        half4v o;
        #pragma unroll
        for (int j = 0; j < 4; ++j) o[j] = (f16)v[j];
        *(half4v*)(xh + i) = o;
        return;
    }
    // ---- W transpose-cast: 1024 blocks = 4 W x (16x16) tiles of 64x64 ----
    __shared__ float tl[64][68];            // 17.4 KB; row stride 272 B (16B-aligned)
    const int b2 = bid - 4096;
    const int z = b2 >> 8;
    const float* W = (z == 0) ? Wq : (z == 1) ? Wk : (z == 2) ? Wv : Wo;
    const int bx = b2 & 15, by = (b2 >> 4) & 15;
    #pragma unroll
    for (int p = 0; p < 4; ++p) {
        int r = (t >> 4) + p * 16;          // 0..63
        int c = (t & 15) * 4;               // 0..60
        floatx4 v = *(const floatx4*)(&W[(size_t)(by * 64 + r) * HIDDEN + bx * 64 + c]);
        *(floatx4*)(&tl[r][c]) = v;
    }
    __syncthreads();
    #pragma unroll
    for (int p = 0; p < 4; ++p) {
        int rr = (t >> 4) + p * 16;         // out row (= W col) 0..63
        int cc = (t & 15) * 4;              // out col (= W row) 0..60
        half4v o;
        o[0] = (f16)tl[cc + 0][rr];
        o[1] = (f16)tl[cc + 1][rr];
        o[2] = (f16)tl[cc + 2][rr];
        o[3] = (f16)tl[cc + 3][rr];
        *(half4v*)(&wt[(size_t)z * HIDDEN * HIDDEN + (size_t)(bx * 64 + rr) * HIDDEN + by * 64 + cc]) = o;
    }
}

// ---------------- fused QKV GEMM (BK=64, global_load_lds staging) ----------------
#define BM 128
#define BN 128
#define GBK 64

__global__ __launch_bounds__(256, 3) void gemm_qkv(const f16* __restrict__ xh,
                                                   const f16* __restrict__ wt,
                                                   const float* __restrict__ bq,
                                                   const float* __restrict__ bk,
                                                   const float* __restrict__ bv,
                                                   f16* __restrict__ qo, f16* __restrict__ ko,
                                                   f16* __restrict__ vto) {
    __shared__ f16 As[BM * GBK];
    __shared__ f16 Bs[BN * GBK];
    const int m0 = blockIdx.y * BM;
    const int n0 = blockIdx.x * BN;
    const int t = threadIdx.x;
    const int lane = t & 63, w = t >> 6;
    const int wm = w >> 1, wn = w & 1;
    const int lr = lane & 15, quad = lane >> 4;
    const int lq7 = lr & 7;

    const int baseA0 = wm * 4096 + lr * 64 + ((quad ^ lq7) * 8);
    const int baseA1 = wm * 4096 + lr * 64 + (((quad + 4) ^ lq7) * 8);
    const int baseB0 = wn * 4096 + lr * 64 + ((quad ^ lq7) * 8);
    const int baseB1 = wn * 4096 + lr * 64 + (((quad + 4) ^ lq7) * 8);

    floatx4 acc[4][4];
    #pragma unroll
    for (int i = 0; i < 4; ++i)
        #pragma unroll
        for (int j = 0; j < 4; ++j)
            #pragma unroll
            for (int r = 0; r < 4; ++r) acc[i][j][r] = 0.f;

    for (int k0 = 0; k0 < HIDDEN; k0 += GBK) {
        #pragma unroll
        for (int p = 0; p < 4; ++p) {
            int s = p * 256 + t;
            int row = s >> 3, ch = (s & 7) ^ (row & 7);
            cp16(&As[s * 8], &xh[(size_t)(m0 + row) * HIDDEN + k0 + ch * 8]);
            cp16(&Bs[s * 8], &wt[(size_t)(n0 + row) * HIDDEN + k0 + ch * 8]);
        }
        __syncthreads();
        half8 af[4], bf[4];
        #pragma unroll
        for (int i = 0; i < 4; ++i) af[i] = *(half8*)(&As[baseA0 + i * 1024]);
        #pragma unroll
        for (int j = 0; j < 4; ++j) bf[j] = *(half8*)(&Bs[baseB0 + j * 1024]);
        #pragma unroll
        for (int i = 0; i < 4; ++i)
            #pragma unroll
            for (int j = 0; j < 4; ++j)
                acc[i][j] = __builtin_amdgcn_mfma_f32_16x16x32_f16(af[i], bf[j], acc[i][j], 0, 0, 0);
        #pragma unroll
        for (int i = 0; i < 4; ++i) af[i] = *(half8*)(&As[baseA1 + i * 1024]);
        #pragma unroll
        for (int j = 0; j < 4; ++j) bf[j] = *(half8*)(&Bs[baseB1 + j * 1024]);
        #pragma unroll
        for (int i = 0; i < 4; ++i)
            #pragma unroll
            for (int j = 0; j < 4; ++j)
                acc[i][j] = __builtin_amdgcn_mfma_f32_16x16x32_f16(af[i], bf[j], acc[i][j], 0, 0, 0);
        __syncthreads();
    }

    #pragma unroll
    for (int i = 0; i < 4; ++i) {
        int mbase = m0 + wm * 64 + i * 16 + quad * 4;
        #pragma unroll
        for (int j = 0; j < 4; ++j) {
            int n = n0 + wn * 64 + j * 16 + lr;
            int proj = n >> 10;
            int c = n & 1023;
            int h = c >> 6, d = c & 63;
            const float* bp = (proj == 0) ? bq : (proj == 1) ? bk : bv;
            float bias = bp[c];
            int m = mbase;
            int b = m >> 11, s = m & 2047;
            int bh = b * HEADS + h;
            if (proj == 2) {
                half4v pv;
                #pragma unroll
                for (int r = 0; r < 4; ++r) pv[r] = (f16)(acc[i][j][r] + bias);
                *(half4v*)(&vto[((size_t)bh * HD + d) * SEQ + s]) = pv;  // natural [d][s]
            } else {
                f16* dst = (proj == 0) ? qo : ko;
                #pragma unroll
                for (int r = 0; r < 4; ++r)
                    dst[((size_t)bh * SEQ + (s + r)) * HD + d] = (f16)(acc[i][j][r] + bias);
            }
        }
    }
}

// ---------------- flash attention v17: 8-wave block, split-K within block ----------------
// (unchanged from round 8: 44.1 us, occupancy 30%, VGPR 64 -- plateaued; see v18 notes)
__global__ __launch_bounds__(512, 4) void attn_kernel(const f16* __restrict__ q,
                                                      const f16* __restrict__ k,
                                                      const f16* __restrict__ vt,
                                                      f16* __restrict__ ctx) {
    __shared__ __align__(16) f16 Klds[2][128 * 64];   // [perm-key][d] swizzled, 2 x 16 KB
    __shared__ __align__(16) f16 Vlds[2][64 * 128];   // [d][s] swizzled, 2 x 16 KB
    const int blk = blockIdx.x;
    const int bh = blk & 31, qt = blk >> 5;   // bh low -> XCD-local
    const int t = threadIdx.x;
    const int lane = t & 63, w = t >> 6;      // 8 waves
    const int qw = w >> 1, kh = w & 1;        // q-group, key-half
    const int lr = lane & 15, quad = lane >> 4;
    const int lq7 = lr & 7;

    const f16* qbh = q + (size_t)bh * SEQ * HD;
    const f16* kbh = k + (size_t)bh * SEQ * HD;
    const f16* vbh = vt + (size_t)bh * HD * SEQ;

    const int qrow = qt * 128 + qw * 32;

    // K fragment bases: key-half kh covers t2-blocks 4*kh..4*kh+3 (f16 offset 4096*kh)
    const int base_k0 = kh * 4096 + lr * 64 + ((quad ^ lq7) * 8);
    const int base_k1 = kh * 4096 + lr * 64 + (((quad + 4) ^ lq7) * 8);
    // V fragment bases for the 2 local key-groups (global g2 = 2*kh + g2l)
    int voff[2];
    #pragma unroll
    for (int g2l = 0; g2l < 2; ++g2l) {
        int g2 = 2 * kh + g2l;
        voff[g2l] = lr * 128 + (((g2 * 4 + quad) ^ lr) * 8);
    }

    // stage tile kt into (Kd, Vd): 4 global_load_lds per thread (2 K + 2 V), 512 threads
    auto stage = [&](f16* Kd, f16* Vd, int kt) {
        const f16* kbase = kbh + (size_t)kt * 128 * HD;
        const f16* vbase = vbh + (size_t)kt * 128;
        #pragma unroll
        for (int p = 0; p < 2; ++p) {
            int s = p * 512 + t;
            int row = s >> 3, ch = (s & 7) ^ (row & 7);
            int wk = row & 31;
            int key = (row & ~31) | ((wk & 12) << 1) | ((wk >> 4) << 2) | (wk & 3);
            cp16(&Kd[s * 8], &kbase[(size_t)key * HD + ch * 8]);
        }
        #pragma unroll
        for (int p = 0; p < 2; ++p) {
            int s = p * 512 + t;
            int row = s >> 4, ch = (s & 15) ^ (row & 15);
            cp16(&Vd[s * 8], &vbase[(size_t)row * SEQ + ch * 8]);
        }
    };

    // issue tile-0 staging first so it overlaps the Q-fragment load + scale math
    stage(Klds[0], Vlds[0], 0);

    // Q fragments pre-scaled by (1/8)*log2(e); group g covers queries qrow+g*16+lr
    half8 qf[2][2];
    #pragma unroll
    for (int g = 0; g < 2; ++g)
        #pragma unroll
        for (int ks = 0; ks < 2; ++ks) {
            half8 v = *(const half8*)(&qbh[(size_t)(qrow + g * 16 + lr) * HD + ks * 32 + quad * 8]);
            #pragma unroll
            for (int j = 0; j < 8; ++j) v[j] = (f16)((float)v[j] * 0.1803368801f);
            qf[g][ks] = v;
        }

    floatx4 oacc[2][4];
    float lsum[2] = {0.f, 0.f};
    #pragma unroll
    for (int g = 0; g < 2; ++g)
        #pragma unroll
        for (int nt4 = 0; nt4 < 4; ++nt4)
            #pragma unroll
            for (int r = 0; r < 4; ++r) oacc[g][nt4][r] = 0.f;

    // tile 0 staged by all waves before first compute
    asm volatile("s_waitcnt vmcnt(0)" ::: "memory");
    __builtin_amdgcn_s_barrier();
    asm volatile("" ::: "memory");

    for (int kt = 0; kt < 16; ++kt) {
        const int cur = kt & 1;
        // prefetch next tile into the other buffer; loads stay in flight across compute
        if (kt < 15) stage(Klds[cur ^ 1], Vlds[cur ^ 1], kt + 1);
        f16* Kl = Klds[cur];
        f16* Vl = Vlds[cur];

        // ---- Phase A: K fragment reads for this wave's key-half (8 x ds_read_b128) ----
        half8 kf[4][2];
        #pragma unroll
        for (int j = 0; j < 4; ++j) {
            kf[j][0] = *(half8*)(&Kl[base_k0 + j * 1024]);
            kf[j][1] = *(half8*)(&Kl[base_k1 + j * 1024]);
        }

        // ---- Phase B: QK^T MFMAs (8 independent 2-deep chains) ----
        floatx4 sc[4][2];
        #pragma unroll
        for (int j = 0; j < 4; ++j) {
            #pragma unroll
            for (int g = 0; g < 2; ++g) {
                floatx4 s = {0.f, 0.f, 0.f, 0.f};
                s = __builtin_amdgcn_mfma_f32_16x16x32_f16(kf[j][0], qf[g][0], s, 0, 0, 0);
                s = __builtin_amdgcn_mfma_f32_16x16x32_f16(kf[j][1], qf[g][1], s, 0, 0, 0);
                sc[j][g] = s;
            }
        }

        // ---- Phase C: exps + packs ----
        half8 p8[2][2];
        #pragma unroll
        for (int g2l = 0; g2l < 2; ++g2l) {
            #pragma unroll
            for (int g = 0; g < 2; ++g) {
                floatx4 s0 = sc[2 * g2l][g], s1 = sc[2 * g2l + 1][g];
                float pa0 = fast_exp2(s0[0]), pa1 = fast_exp2(s0[1]);
                float pa2 = fast_exp2(s0[2]), pa3 = fast_exp2(s0[3]);
                float pb0 = fast_exp2(s1[0]), pb1 = fast_exp2(s1[1]);
                float pb2 = fast_exp2(s1[2]), pb3 = fast_exp2(s1[3]);
                lsum[g] += ((pa0 + pa1) + (pa2 + pa3)) + ((pb0 + pb1) + (pb2 + pb3));
                half4v pa = __builtin_shufflevector(pk_f16(pa0, pa1), pk_f16(pa2, pa3), 0, 1, 2, 3);
                half4v pb = __builtin_shufflevector(pk_f16(pb0, pb1), pk_f16(pb2, pb3), 0, 1, 2, 3);
                p8[g2l][g] = __builtin_shufflevector(pa, pb, 0, 1, 2, 3, 4, 5, 6, 7);
            }
        }

        // ---- Phase D: V reads for this key-half, then PV MFMAs ----
        half8 vf[2][4];
        #pragma unroll
        for (int g2l = 0; g2l < 2; ++g2l)
            #pragma unroll
            for (int nt4 = 0; nt4 < 4; ++nt4)
                vf[g2l][nt4] = *(half8*)(&Vl[voff[g2l] + nt4 * 2048]);
        #pragma unroll
        for (int g2l = 0; g2l < 2; ++g2l)
            #pragma unroll
            for (int nt4 = 0; nt4 < 4; ++nt4) {
                oacc[0][nt4] = __builtin_amdgcn_mfma_f32_16x16x32_f16(vf[g2l][nt4], p8[g2l][0], oacc[0][nt4], 0, 0, 0);
                oacc[1][nt4] = __builtin_amdgcn_mfma_f32_16x16x32_f16(vf[g2l][nt4], p8[g2l][1], oacc[1][nt4], 0, 0, 0);
            }

        // single end-of-tile sync: (a) prefetch for kt+1 landed (per-wave vmcnt + barrier),
        // (b) all waves done reading buf[cur] before kt+1 overwrites it.
        asm volatile("s_waitcnt vmcnt(0)" ::: "memory");
        __builtin_amdgcn_s_barrier();
        asm volatile("" ::: "memory");
    }

    // ---- combine kh partials via LDS (once), then normalize + store ----
    // All ds_reads of the loop completed before its final barrier; Klds/Vlds reusable.
    floatx4* XO = (floatx4*)(&Klds[0][0]);   // 8 x 256 floatx4 = 32 KB (oacc exchange)
    float*   XL = (float*)(&Vlds[0][0]);     // 2 KB (lsum exchange)
    if (kh == 1) {
        #pragma unroll
        for (int g = 0; g < 2; ++g)
            #pragma unroll
            for (int nt4 = 0; nt4 < 4; ++nt4)
                XO[(g * 4 + nt4) * 256 + qw * 64 + lane] = oacc[g][nt4];
        XL[(qw * 64 + lane) * 2 + 0] = lsum[0];
        XL[(qw * 64 + lane) * 2 + 1] = lsum[1];
    }
    __syncthreads();
    if (kh == 0) {
        #pragma unroll
        for (int g = 0; g < 2; ++g)
            #pragma unroll
            for (int nt4 = 0; nt4 < 4; ++nt4) {
                floatx4 o = XO[(g * 4 + nt4) * 256 + qw * 64 + lane];
                #pragma unroll
                for (int r = 0; r < 4; ++r) oacc[g][nt4][r] += o[r];
            }
        lsum[0] += XL[(qw * 64 + lane) * 2 + 0];
        lsum[1] += XL[(qw * 64 + lane) * 2 + 1];

        const int b = bh >> 4, h = bh & 15;
        #pragma unroll
        for (int g = 0; g < 2; ++g) {
            float s = lsum[g];
            s += __shfl_xor(s, 16, 64);
            s += __shfl_xor(s, 32, 64);
            float inv = 1.f / s;
            #pragma unroll
            for (int nt4 = 0; nt4 < 4; ++nt4) {
                half4v o4;
                #pragma unroll
                for (int r = 0; r < 4; ++r) o4[r] = (f16)(oacc[g][nt4][r] * inv);
                *(half4v*)(&ctx[((size_t)(b * SEQ + qrow + g * 16 + lr)) * HIDDEN + h * HD + nt4 * 16 + quad * 4]) = o4;
            }
        }
    }
}

// ---------------- output projection GEMM (64x128 tiles, BK=64, fp32 out) ----------------
#define OBM 64
__global__ __launch_bounds__(256, 4) void gemm_out(const f16* __restrict__ ah,
                                                   const f16* __restrict__ wto,
                                                   const float* __restrict__ bo,
                                                   float* __restrict__ out) {
    __shared__ f16 As[OBM * GBK];   // 8 KB
    __shared__ f16 Bs[BN * GBK];    // 16 KB
    const int m0 = blockIdx.y * OBM;
    const int n0 = blockIdx.x * BN;
    const int t = threadIdx.x;
    const int lane = t & 63, w = t >> 6;
    const int wm = w >> 1, wn = w & 1;   // wave tile: 32 m x 64 n
    const int lr = lane & 15, quad = lane >> 4;
    const int lq7 = lr & 7;

    const int baseA0 = wm * 2048 + lr * 64 + ((quad ^ lq7) * 8);
    const int baseA1 = wm * 2048 + lr * 64 + (((quad + 4) ^ lq7) * 8);
    const int baseB0 = wn * 4096 + lr * 64 + ((quad ^ lq7) * 8);
    const int baseB1 = wn * 4096 + lr * 64 + (((quad + 4) ^ lq7) * 8);

    floatx4 acc[2][4];
    #pragma unroll
    for (int i = 0; i < 2; ++i)
        #pragma unroll
        for (int j = 0; j < 4; ++j)
            #pragma unroll
            for (int r = 0; r < 4; ++r) acc[i][j][r] = 0.f;

    for (int k0 = 0; k0 < HIDDEN; k0 += GBK) {
        #pragma unroll
        for (int p = 0; p < 2; ++p) {
            int s = p * 256 + t;
            int row = s >> 3, ch = (s & 7) ^ (row & 7);
            cp16(&As[s * 8], &ah[(size_t)(m0 + row) * HIDDEN + k0 + ch * 8]);
        }
        #pragma unroll
        for (int p = 0; p < 4; ++p) {
            int s = p * 256 + t;
            int row = s >> 3, ch = (s & 7) ^ (row & 7);
            cp16(&Bs[s * 8], &wto[(size_t)(n0 + row) * HIDDEN + k0 + ch * 8]);
        }
        __syncthreads();
        half8 af[2], bf[4];
        #pragma unroll
        for (int i = 0; i < 2; ++i) af[i] = *(half8*)(&As[baseA0 + i * 1024]);
        #pragma unroll
        for (int j = 0; j < 4; ++j) bf[j] = *(half8*)(&Bs[baseB0 + j * 1024]);
        #pragma unroll
        for (int i = 0; i < 2; ++i)
            #pragma unroll
            for (int j = 0; j < 4; ++j)
                acc[i][j] = __builtin_amdgcn_mfma_f32_16x16x32_f16(af[i], bf[j], acc[i][j], 0, 0, 0);
        #pragma unroll
        for (int i = 0; i < 2; ++i) af[i] = *(half8*)(&As[baseA1 + i * 1024]);
        #pragma unroll
        for (int j = 0; j < 4; ++j) bf[j] = *(half8*)(&Bs[baseB1 + j * 1024]);
        #pragma unroll
        for (int i = 0; i < 2; ++i)
            #pragma unroll
            for (int j = 0; j < 4; ++j)
                acc[i][j] = __builtin_amdgcn_mfma_f32_16x16x32_f16(af[i], bf[j], acc[i][j], 0, 0, 0);
        __syncthreads();
    }

    #pragma unroll
    for (int i = 0; i < 2; ++i) {
        int mbase = m0 + wm * 32 + i * 16 + quad * 4;
        #pragma unroll
        for (int j = 0; j < 4; ++j) {
            int n = n0 + wn * 64 + j * 16 + lr;
            float bias = bo[n];
            #pragma unroll
            for (int r = 0; r < 4; ++r)
                out[(size_t)(mbase + r) * HIDDEN + n] = acc[i][j][r] + bias;
        }
    }
}

// ---------------- launch ----------------
extern "C" void kernel_launch(void* const* d_in, const int* in_sizes, int n_in,
                              void* d_out, int out_size, void* d_ws, size_t ws_size,
                              hipStream_t stream) {
    const float* x  = (const float*)d_in[0];
    const float* Wq = (const float*)d_in[1];
    const float* bq = (const float*)d_in[2];
    const float* Wk = (const float*)d_in[3];
    const float* bk = (const float*)d_in[4];
    const float* Wv = (const float*)d_in[5];
    const float* bv = (const float*)d_in[6];
    const float* Wo = (const float*)d_in[7];
    const float* bo = (const float*)d_in[8];
    float* out = (float*)d_out;

    char* ws = (char*)d_ws;
    f16* xh   = (f16*)(ws);                   // 8 MB
    f16* wt   = (f16*)(ws + (8u  << 20));     // 8 MB
    f16* qw   = (f16*)(ws + (16u << 20));     // 8 MB
    f16* kw   = (f16*)(ws + (24u << 20));     // 8 MB
    f16* vtw  = (f16*)(ws + (32u << 20));     // 8 MB (natural [d][s] layout)
    f16* ctxh = (f16*)(ws + (40u << 20));     // 8 MB

    prep_kernel<<<4096 + 1024, 256, 0, stream>>>(x, Wq, Wk, Wv, Wo, xh, wt);
    gemm_qkv<<<dim3(3 * HIDDEN / BN, MTOT / BM), 256, 0, stream>>>(xh, wt, bq, bk, bv, qw, kw, vtw);
    attn_kernel<<<32 * (SEQ / 128), 512, 0, stream>>>(qw, kw, vtw, ctxh);
    gemm_out<<<dim3(HIDDEN / BN, MTOT / OBM), 256, 0, stream>>>(ctxh, wt + (size_t)3 * HIDDEN * HIDDEN, bo, out);
}